// Round 1
// baseline (389.349 us; speedup 1.0000x reference)
//
#include <hip/hip_runtime.h>

#define NB 64
#define NC 512
#define NPTS 3000
#define MAXH 70
#define MAXW 40
#define HW (MAXH * MAXW)   // 2800
#define CPB 8              // channels per block
#define THREADS 256
#define FIXCAP 8192

// reset the fixup counter (ws is NOT re-poisoned between replays)
__global__ void fm_zero_cnt(int* cnt) {
    if (threadIdx.x == 0) cnt[0] = 0;
}

__launch_bounds__(THREADS)
__global__ void fm_gather_kernel(const float* __restrict__ feat,
                                 const int* __restrict__ ys,
                                 const int* __restrict__ xs,
                                 float* __restrict__ out,
                                 int* __restrict__ fix_cnt,
                                 int* __restrict__ fix_list,
                                 int fix_cap)
{
    __shared__ int inv_s[HW];      // cell -> point index (or -1)
    __shared__ int s_red[16];      // 4 quantities x 4 waves
    __shared__ int s_par[5];       // swap, minY, minX, row_off, col_off

    const int blocks_per_b = NC / CPB;
    const int b   = blockIdx.x / blocks_per_b;
    const int c0  = (blockIdx.x % blocks_per_b) * CPB;
    const int tid = threadIdx.x;
    const int lane = tid & 63;
    const int wid  = tid >> 6;

    const int* ysb = ys + b * NPTS;
    const int* xsb = xs + b * NPTS;

    // ---- phase 0: per-batch min/max over valid points (ys > -1) ----
    int vminY = 0x7fffffff, vminX = 0x7fffffff;
    int vmaxY = -0x7fffffff, vmaxX = -0x7fffffff;
    for (int n = tid; n < NPTS; n += THREADS) {
        int y = ysb[n];
        int x = xsb[n];
        if (y > -1) {
            vminY = min(vminY, y); vmaxY = max(vmaxY, y);
            vminX = min(vminX, x); vmaxX = max(vmaxX, x);
        }
    }
#pragma unroll
    for (int off = 32; off > 0; off >>= 1) {
        vminY = min(vminY, __shfl_xor(vminY, off));
        vmaxY = max(vmaxY, __shfl_xor(vmaxY, off));
        vminX = min(vminX, __shfl_xor(vminX, off));
        vmaxX = max(vmaxX, __shfl_xor(vmaxX, off));
    }
    if (lane == 0) {
        s_red[wid]      = vminY;
        s_red[4  + wid] = vmaxY;
        s_red[8  + wid] = vminX;
        s_red[12 + wid] = vmaxX;
    }
    __syncthreads();
    if (tid == 0) {
        int mnY = min(min(s_red[0], s_red[1]),  min(s_red[2],  s_red[3]));
        int mxY = max(max(s_red[4], s_red[5]),  max(s_red[6],  s_red[7]));
        int mnX = min(min(s_red[8], s_red[9]),  min(s_red[10], s_red[11]));
        int mxX = max(max(s_red[12], s_red[13]), max(s_red[14], s_red[15]));
        int h = mxY - mnY + 1;
        int w = mxX - mnX + 1;
        int swap = (w > h) ? 1 : 0;
        int H0 = swap ? w : h;
        int W0 = swap ? h : w;
        int h_dif = H0 - MAXH;
        int w_dif = W0 - MAXW;
        int cut_top  = (h_dif > 0) ? (h_dif + 1) / 2 : 0;
        int pad_top  = (h_dif > 0) ? 0 : (-h_dif + 1) / 2;
        int cut_left = (w_dif > 0) ? (w_dif + 1) / 2 : 0;
        int left_pad = (w_dif > 0) ? 0 : (-w_dif + 1) / 2;  // ref applies "pad_right" on the LEFT
        s_par[0] = swap;
        s_par[1] = mnY;
        s_par[2] = mnX;
        s_par[3] = pad_top - cut_top;
        s_par[4] = left_pad - cut_left;
    }

    // ---- phase 1: build inverse map in LDS ----
    for (int i = tid; i < HW; i += THREADS) inv_s[i] = -1;
    __syncthreads();
    {
        const int swp = s_par[0], mnY = s_par[1], mnX = s_par[2];
        const int roff = s_par[3], coff = s_par[4];
        for (int n = tid; n < NPTS; n += THREADS) {
            int y = ysb[n];
            int x = xsb[n];
            if (y > -1) {
                int r  = swp ? (x - mnX) : (y - mnY);
                int cl = swp ? (y - mnY) : (x - mnX);
                int rr = r + roff;
                int cc = cl + coff;
                if (rr >= 0 && rr < MAXH && cc >= 0 && cc < MAXW)
                    inv_s[rr * MAXW + cc] = n;   // unique targets per setup
            }
        }
    }
    __syncthreads();

    // ---- phase 2: gather + coalesced float4 stores ----
    for (int c = c0; c < c0 + CPB; ++c) {
        const float* __restrict__ frow = feat + (size_t)(b * NC + c) * NPTS;
        float* __restrict__ orow = out + (size_t)(b * NC + c) * HW;
        for (int i4 = tid; i4 < HW / 4; i4 += THREADS) {
            float4 v;
            float* vp = &v.x;
#pragma unroll
            for (int j = 0; j < 4; ++j) {
                int cell = i4 * 4 + j;
                int n = inv_s[cell];
                float val = 0.0f;
                if (n >= 0) {
                    val = frow[n];
                    if (val == -1.0f) {
                        // scattered cell containing exact -1.0 -> whole cell must be zeroed
                        int pos = atomicAdd(fix_cnt, 1);
                        if (pos < fix_cap) fix_list[pos] = b * HW + cell;
                    }
                }
                vp[j] = val;
            }
            *reinterpret_cast<float4*>(orow + i4 * 4) = v;
        }
    }
}

__global__ void fm_fixup_kernel(const int* __restrict__ fix_cnt,
                                const int* __restrict__ fix_list,
                                int fix_cap,
                                float* __restrict__ out)
{
    int count = min(fix_cnt[0], fix_cap);
    long total = (long)count * NC;
    long stride = (long)gridDim.x * blockDim.x;
    for (long t = (long)blockIdx.x * blockDim.x + threadIdx.x; t < total; t += stride) {
        int e = (int)(t / NC);
        int c = (int)(t % NC);
        int cell = fix_list[e];
        int b   = cell / HW;
        int pos = cell % HW;
        out[(size_t)(b * NC + c) * HW + pos] = 0.0f;
    }
}

extern "C" void kernel_launch(void* const* d_in, const int* in_sizes, int n_in,
                              void* d_out, int out_size, void* d_ws, size_t ws_size,
                              hipStream_t stream) {
    const float* feat = (const float*)d_in[0];
    const int*   ys   = (const int*)d_in[1];
    const int*   xs   = (const int*)d_in[2];
    float* out = (float*)d_out;

    int* fix_cnt  = (int*)d_ws;
    int* fix_list = (int*)((char*)d_ws + 16);
    int fix_cap = 0;
    if (ws_size > 16) {
        size_t avail = (ws_size - 16) / 4;
        fix_cap = (int)((avail < FIXCAP) ? avail : FIXCAP);
    }

    fm_zero_cnt<<<1, 64, 0, stream>>>(fix_cnt);

    int grid = NB * (NC / CPB);  // 64 * 64 = 4096
    fm_gather_kernel<<<grid, THREADS, 0, stream>>>(feat, ys, xs, out,
                                                   fix_cnt, fix_list, fix_cap);

    fm_fixup_kernel<<<128, 256, 0, stream>>>(fix_cnt, fix_list, fix_cap, out);
}

// Round 2
// 172.207 us; speedup vs baseline: 2.2609x; 2.2609x over previous
//
#include <hip/hip_runtime.h>

#define NB 64
#define NC 512
#define NPTS 3000
#define MAXH 70
#define MAXW 40
#define HW (MAXH * MAXW)   // 2800
#define CPB 16             // channels per block
#define THREADS 256
#define FIXCAP 8192
#define NV4 (NPTS / 4)     // 750 float4 per feature row
#define OV4 (HW / 4)       // 700 float4 per output row

// reset the fixup counter (ws is NOT re-poisoned between replays)
__global__ void fm_zero_cnt(int* cnt) {
    if (threadIdx.x == 0) cnt[0] = 0;
}

__launch_bounds__(THREADS)
__global__ void fm_gather_kernel(const float* __restrict__ feat,
                                 const int* __restrict__ ys,
                                 const int* __restrict__ xs,
                                 float* __restrict__ out,
                                 int* __restrict__ fix_cnt,
                                 int* __restrict__ fix_list,
                                 int fix_cap)
{
    __shared__ int    inv_s[HW];        // cell -> point index (or -1), 11.2 KB
    __shared__ float4 fbuf[2][NV4];     // double-buffered feature row, 24 KB
    __shared__ int    s_red[16];
    __shared__ int    s_par[5];

    const int blocks_per_b = NC / CPB;            // 32
    const int b   = blockIdx.x / blocks_per_b;
    const int c0  = (blockIdx.x % blocks_per_b) * CPB;
    const int tid = threadIdx.x;
    const int lane = tid & 63;
    const int wid  = tid >> 6;

    const int* ysb = ys + b * NPTS;
    const int* xsb = xs + b * NPTS;
    int* ybuf = (int*)fbuf[0];   // coords parked in the feature buffers
    int* xbuf = (int*)fbuf[1];   // (3000 ints = 12000 B = exactly one buffer)

    // ---- phase 0: coalesced coord load -> LDS, fused min/max; init inv ----
    int vminY = 0x7fffffff, vminX = 0x7fffffff;
    int vmaxY = -0x7fffffff, vmaxX = -0x7fffffff;
    for (int i = tid; i < NV4; i += THREADS) {
        int4 ya = ((const int4*)ysb)[i];
        int4 xa = ((const int4*)xsb)[i];
        ((int4*)ybuf)[i] = ya;
        ((int4*)xbuf)[i] = xa;
        int yv[4] = {ya.x, ya.y, ya.z, ya.w};
        int xv[4] = {xa.x, xa.y, xa.z, xa.w};
#pragma unroll
        for (int j = 0; j < 4; ++j) {
            if (yv[j] > -1) {
                vminY = min(vminY, yv[j]); vmaxY = max(vmaxY, yv[j]);
                vminX = min(vminX, xv[j]); vmaxX = max(vmaxX, xv[j]);
            }
        }
    }
    for (int i = tid; i < HW; i += THREADS) inv_s[i] = -1;
#pragma unroll
    for (int off = 32; off > 0; off >>= 1) {
        vminY = min(vminY, __shfl_xor(vminY, off));
        vmaxY = max(vmaxY, __shfl_xor(vmaxY, off));
        vminX = min(vminX, __shfl_xor(vminX, off));
        vmaxX = max(vmaxX, __shfl_xor(vmaxX, off));
    }
    if (lane == 0) {
        s_red[wid]      = vminY;
        s_red[4  + wid] = vmaxY;
        s_red[8  + wid] = vminX;
        s_red[12 + wid] = vmaxX;
    }
    __syncthreads();
    if (tid == 0) {
        int mnY = min(min(s_red[0], s_red[1]),   min(s_red[2],  s_red[3]));
        int mxY = max(max(s_red[4], s_red[5]),   max(s_red[6],  s_red[7]));
        int mnX = min(min(s_red[8], s_red[9]),   min(s_red[10], s_red[11]));
        int mxX = max(max(s_red[12], s_red[13]), max(s_red[14], s_red[15]));
        int h = mxY - mnY + 1;
        int w = mxX - mnX + 1;
        int swap = (w > h) ? 1 : 0;
        int H0 = swap ? w : h;
        int W0 = swap ? h : w;
        int h_dif = H0 - MAXH;
        int w_dif = W0 - MAXW;
        int cut_top  = (h_dif > 0) ? (h_dif + 1) / 2 : 0;
        int pad_top  = (h_dif > 0) ? 0 : (-h_dif + 1) / 2;
        int cut_left = (w_dif > 0) ? (w_dif + 1) / 2 : 0;
        int left_pad = (w_dif > 0) ? 0 : (-w_dif + 1) / 2; // ref pads "right" on the LEFT
        s_par[0] = swap;
        s_par[1] = mnY;
        s_par[2] = mnX;
        s_par[3] = pad_top - cut_top;
        s_par[4] = left_pad - cut_left;
    }
    __syncthreads();

    // ---- phase 1: build inverse map from LDS coords ----
    {
        const int swp = s_par[0], mnY = s_par[1], mnX = s_par[2];
        const int roff = s_par[3], coff = s_par[4];
        for (int n = tid; n < NPTS; n += THREADS) {
            int y = ybuf[n];
            int x = xbuf[n];
            if (y > -1) {
                int r  = swp ? (x - mnX) : (y - mnY);
                int cl = swp ? (y - mnY) : (x - mnX);
                int rr = r + roff;
                int cc = cl + coff;
                if (rr >= 0 && rr < MAXH && cc >= 0 && cc < MAXW)
                    inv_s[rr * MAXW + cc] = n;   // unique targets per setup
            }
        }
    }
    __syncthreads();

    // ---- phase 2: hoist channel-invariant inv lookups to registers,
    //               stage first channel ----
    int nreg[3][4];
#pragma unroll
    for (int it = 0; it < 3; ++it) {
        int i4 = it * THREADS + tid;
        if (i4 < OV4) {
#pragma unroll
            for (int j = 0; j < 4; ++j) nreg[it][j] = inv_s[i4 * 4 + j];
        }
    }
    {
        const float4* src = (const float4*)(feat + (size_t)(b * NC + c0) * NPTS);
#pragma unroll
        for (int it = 0; it < 3; ++it) {
            int i = it * THREADS + tid;
            if (i < NV4) fbuf[0][i] = src[i];
        }
    }
    __syncthreads();

    // ---- phase 3: per-channel LDS gather + coalesced float4 stores ----
    for (int ci = 0; ci < CPB; ++ci) {
        const int cur = ci & 1;
        if (ci + 1 < CPB) {   // prefetch next channel into the other buffer
            const float4* src =
                (const float4*)(feat + (size_t)(b * NC + c0 + ci + 1) * NPTS);
#pragma unroll
            for (int it = 0; it < 3; ++it) {
                int i = it * THREADS + tid;
                if (i < NV4) fbuf[cur ^ 1][i] = src[i];
            }
        }
        const float* fp = (const float*)fbuf[cur];
        float* orow = out + (size_t)(b * NC + c0 + ci) * HW;
#pragma unroll
        for (int it = 0; it < 3; ++it) {
            int i4 = it * THREADS + tid;
            if (i4 < OV4) {
                float4 v;
                float* vp = &v.x;
#pragma unroll
                for (int j = 0; j < 4; ++j) {
                    int n = nreg[it][j];
                    float val = 0.0f;
                    if (n >= 0) {
                        val = fp[n];
                        if (val == -1.0f) {
                            // scattered cell containing exact -1.0 -> zero whole cell
                            int pos = atomicAdd(fix_cnt, 1);
                            if (pos < fix_cap) fix_list[pos] = b * HW + i4 * 4 + j;
                        }
                    }
                    vp[j] = val;
                }
                ((float4*)orow)[i4] = v;
            }
        }
        __syncthreads();
    }
}

__global__ void fm_fixup_kernel(const int* __restrict__ fix_cnt,
                                const int* __restrict__ fix_list,
                                int fix_cap,
                                float* __restrict__ out)
{
    int count = min(fix_cnt[0], fix_cap);
    long total = (long)count * NC;
    long stride = (long)gridDim.x * blockDim.x;
    for (long t = (long)blockIdx.x * blockDim.x + threadIdx.x; t < total; t += stride) {
        int e = (int)(t / NC);
        int c = (int)(t % NC);
        int cell = fix_list[e];
        int b   = cell / HW;
        int pos = cell % HW;
        out[(size_t)(b * NC + c) * HW + pos] = 0.0f;
    }
}

extern "C" void kernel_launch(void* const* d_in, const int* in_sizes, int n_in,
                              void* d_out, int out_size, void* d_ws, size_t ws_size,
                              hipStream_t stream) {
    const float* feat = (const float*)d_in[0];
    const int*   ys   = (const int*)d_in[1];
    const int*   xs   = (const int*)d_in[2];
    float* out = (float*)d_out;

    int* fix_cnt  = (int*)d_ws;
    int* fix_list = (int*)((char*)d_ws + 16);
    int fix_cap = 0;
    if (ws_size > 16) {
        size_t avail = (ws_size - 16) / 4;
        fix_cap = (int)((avail < FIXCAP) ? avail : FIXCAP);
    }

    fm_zero_cnt<<<1, 64, 0, stream>>>(fix_cnt);

    int grid = NB * (NC / CPB);  // 64 * 32 = 2048
    fm_gather_kernel<<<grid, THREADS, 0, stream>>>(feat, ys, xs, out,
                                                   fix_cnt, fix_list, fix_cap);

    fm_fixup_kernel<<<128, 256, 0, stream>>>(fix_cnt, fix_list, fix_cap, out);
}